// Round 1
// 210.941 us; speedup vs baseline: 1.0160x; 1.0160x over previous
//
#include <hip/hip_runtime.h>
#include <stdint.h>

#define B_DIM 8
#define N_DIM 2048
#define F_DIM 128
#define LN_EPS 1e-5f

typedef __attribute__((ext_vector_type(8))) short short8;
typedef __attribute__((ext_vector_type(4))) float floatx4;

// full RNE fp32 -> bf16
__device__ __forceinline__ ushort f2bf(float f) {
    union { float f; uint32_t u; } c;
    c.f = f;
    uint32_t u = c.u;
    return (ushort)((u + 0x7FFFu + ((u >> 16) & 1u)) >> 16);
}

// fast round-half-up pack of two fp32 -> packed bf16x2
__device__ __forceinline__ uint32_t pk2bf(float a, float b) {
    union { float f; uint32_t u; } x, y;
    x.f = a; y.f = b;
    return ((x.u + 0x8000u) >> 16) | ((y.u + 0x8000u) & 0xFFFF0000u);
}

__device__ __forceinline__ short8 pack8(float4 lo, float4 hi) {
    union { uint32_t u[4]; short8 s; } r;
    r.u[0] = pk2bf(lo.x, lo.y);
    r.u[1] = pk2bf(lo.z, lo.w);
    r.u[2] = pk2bf(hi.x, hi.y);
    r.u[3] = pk2bf(hi.z, hi.w);
    return r.s;
}

__device__ __forceinline__ void load_lds16(const ushort* g, ushort* l) {
    __builtin_amdgcn_global_load_lds(
        (const __attribute__((address_space(1))) void*)g,
        (__attribute__((address_space(3))) void*)l,
        16, 0, 0);
}

// ---------------------------------------------------------------------------
// Kernel 1: X (B, K=2048, F=128) fp32 -> Xt (B, F=128, K=2048) bf16.
// ---------------------------------------------------------------------------
__global__ __launch_bounds__(256) void k_transpose(const float* __restrict__ X,
                                                   ushort* __restrict__ Xt) {
    __shared__ ushort tile[64 * 65];
    const int t = threadIdx.x;
    const int b = blockIdx.z;
    const int k0 = blockIdx.x * 64;
    const int f0 = blockIdx.y * 64;

#pragma unroll
    for (int p = 0; p < 2; ++p) {
        int idx = p * 256 + t;
        int kk = idx >> 3;
        int ff = (idx & 7) * 8;
        const float* src = X + (((size_t)b * N_DIM) + k0 + kk) * F_DIM + f0 + ff;
        float4 v0 = *(const float4*)(src);
        float4 v1 = *(const float4*)(src + 4);
        ushort* d = tile + kk * 65 + ff;
        d[0] = f2bf(v0.x); d[1] = f2bf(v0.y); d[2] = f2bf(v0.z); d[3] = f2bf(v0.w);
        d[4] = f2bf(v1.x); d[5] = f2bf(v1.y); d[6] = f2bf(v1.z); d[7] = f2bf(v1.w);
    }
    __syncthreads();

    union U { uint4 v; ushort s[8]; };
#pragma unroll
    for (int p = 0; p < 2; ++p) {
        int idx = p * 256 + t;
        int f2 = idx >> 3;
        int kk2 = (idx & 7) * 8;
        U u;
#pragma unroll
        for (int j = 0; j < 8; ++j) u.s[j] = tile[(kk2 + j) * 65 + f2];
        *(uint4*)(Xt + (((size_t)b * F_DIM) + f0 + f2) * N_DIM + k0 + kk2) = u.v;
    }
}

// ---------------------------------------------------------------------------
// Kernel 2 (fused): H = A@X (bf16 MFMA), P = H@W^T + b, LN(128), ReLU.
// BM=32, BN=128, BK=128.  256 thr = 4 waves; wave w owns cols w*32..+32.
//
// v2: software-pipelined double-buffer (T3 minimum 2-phase + T4 counted vmcnt):
//   per tile: issue glds B(t+1)->buf^1, issue A(t+2) reg loads (depth-2),
//   compute(buf), pack A(t+1)->As[buf^1], s_waitcnt vmcnt(4) lgkmcnt(0),
//   raw s_barrier.  A reg loads survive the barrier (budget ~2 tiles ~1000cy
//   > ~900cy HBM latency); glds (L2-hot) are covered by the MFMA phase.
//   One barrier per tile instead of two full-drain barriers.
// LDS: As 8KBx2 + Bs 32KBx2 = 80 KB; epilogue Ht/Pt alias the stage buffers
//   (dead after K-loop) -> 2 blocks/CU (160 KB), same occupancy as before.
// ---------------------------------------------------------------------------
__global__ __launch_bounds__(256) void k_fused(const float* __restrict__ A,
                                               const ushort* __restrict__ Xt,
                                               const float* __restrict__ W,
                                               const float* __restrict__ bias,
                                               const float* __restrict__ gamma,
                                               const float* __restrict__ beta,
                                               float* __restrict__ out) {
    __shared__ __align__(16) char smem[81920];
    ushort* const As0 = (ushort*)smem;                    // 32x128 bf16, buf0
    ushort* const As1 = (ushort*)(smem + 8192);           // buf1
    ushort* const Bs0 = (ushort*)(smem + 16384);          // 128x128 bf16, buf0
    ushort* const Bs1 = (ushort*)(smem + 16384 + 32768);  // buf1
    // epilogue aliases (valid after final barrier):
    ushort* const Ht = (ushort*)smem;                     // 32*136 bf16 = 8704 B
    float (*const Pt)[132] = (float(*)[132])(smem + 16384);  // 32*132 f32

    const int t = threadIdx.x;
    const int lane = t & 63;
    const int w = t >> 6;            // wave 0..3
    const int q = lane >> 4;         // 0..3
    const int mr = lane & 15;        // 0..15

    const int bid = blockIdx.x;
    const int bb = bid & 7;          // batch -> XCD affinity (L2 keeps Xt slice)
    const int m0 = (bid >> 3) * 32;  // M-tile origin

    const float* Ab = A + ((size_t)bb * N_DIM + m0) * N_DIM;
    const ushort* Xb = Xt + (size_t)bb * F_DIM * N_DIM;

    // A staging map: thread t -> row (t>>3), 16 fp32 at k=(t&7)*16 (coalesced)
    const int arow = t >> 3;
    const int asw_ = arow & 7;
    const float* a_src = Ab + (size_t)arow * N_DIM + (t & 7) * 16;
    const int a_off0 = arow * 128 + ((((t & 7) * 2) ^ asw_) * 8);
    const int a_off1 = arow * 128 + ((((t & 7) * 2 + 1) ^ asw_) * 8);

    // B staging map: 8 glds chunks per thread; LDS slot c = p*256+t (contig
    // per wave as required), source chunk kc = (c&15) ^ (n&7), n = c>>4.
    const ushort* b_src[8];
    int b_off[8];
#pragma unroll
    for (int p = 0; p < 8; ++p) {
        int c = p * 256 + t;
        int n = c >> 4;
        int kc = (c & 15) ^ (n & 7);
        b_src[p] = Xb + (size_t)n * N_DIM + kc * 8;
        b_off[p] = c * 8;
    }

    floatx4 acc[2][2];
#pragma unroll
    for (int i = 0; i < 2; ++i)
#pragma unroll
        for (int j = 0; j < 2; ++j) acc[i][j] = (floatx4){0.f, 0.f, 0.f, 0.f};

    auto stageB = [&](int k0, ushort* Bn) {
#pragma unroll
        for (int p = 0; p < 8; ++p) load_lds16(b_src[p] + k0, Bn + b_off[p]);
    };
    auto packA = [&](float4 v0, float4 v1, float4 v2, float4 v3, ushort* An) {
        *(short8*)(An + a_off0) = pack8(v0, v1);
        *(short8*)(An + a_off1) = pack8(v2, v3);
    };
    auto compute = [&](const ushort* Ac, const ushort* Bc) {
#pragma unroll
        for (int ks = 0; ks < 4; ++ks) {
            short8 af[2], bfr[2];
#pragma unroll
            for (int i = 0; i < 2; ++i) {
                int m = mr + i * 16;
                af[i] = *(const short8*)(Ac + m * 128 + (((ks * 4 + q) ^ (m & 7)) * 8));
            }
#pragma unroll
            for (int j = 0; j < 2; ++j) {
                int n = w * 32 + j * 16 + mr;
                bfr[j] = *(const short8*)(Bc + n * 128 + (((ks * 4 + q) ^ (n & 7)) * 8));
            }
#pragma unroll
            for (int i = 0; i < 2; ++i)
#pragma unroll
                for (int j = 0; j < 2; ++j)
                    acc[i][j] = __builtin_amdgcn_mfma_f32_16x16x32_bf16(
                        af[i], bfr[j], acc[i][j], 0, 0, 0);
        }
    };

    float4 r0a, r0b, r0c, r0d, r1a, r1b, r1c, r1d;

    // ---- prologue: tile 0 -> buf0; issue A(1) regs (left in flight)
    {
        const float4* ap = (const float4*)(a_src);
        r0a = ap[0]; r0b = ap[1]; r0c = ap[2]; r0d = ap[3];
        stageB(0, Bs0);
        packA(r0a, r0b, r0c, r0d, As0);
        __builtin_amdgcn_sched_barrier(0);  // pin: A(1) loads issued AFTER glds
        const float4* ap1 = (const float4*)(a_src + 128);
        r1a = ap1[0]; r1b = ap1[1]; r1c = ap1[2]; r1d = ap1[3];
    }
    asm volatile("s_waitcnt vmcnt(4) lgkmcnt(0)" ::: "memory");
    __builtin_amdgcn_s_barrier();

    // ---- main loop: tiles 0..13 (unroll x2: even->buf0, odd->buf1)
#pragma unroll 1
    for (int tt = 0; tt < 14; tt += 2) {
        const int k0 = tt * 128;
        // even sub-iter: compute tile tt (buf0)
        stageB(k0 + 128, Bs1);
        __builtin_amdgcn_sched_barrier(0);  // pin: reg loads after glds
        {
            const float4* ap = (const float4*)(a_src + k0 + 256);
            r0a = ap[0]; r0b = ap[1]; r0c = ap[2]; r0d = ap[3];
        }
        compute(As0, Bs0);
        packA(r1a, r1b, r1c, r1d, As1);
        asm volatile("s_waitcnt vmcnt(4) lgkmcnt(0)" ::: "memory");
        __builtin_amdgcn_s_barrier();

        // odd sub-iter: compute tile tt+1 (buf1)
        stageB(k0 + 256, Bs0);
        __builtin_amdgcn_sched_barrier(0);
        {
            const float4* ap = (const float4*)(a_src + k0 + 384);
            r1a = ap[0]; r1b = ap[1]; r1c = ap[2]; r1d = ap[3];
        }
        compute(As1, Bs1);
        packA(r0a, r0b, r0c, r0d, As0);
        asm volatile("s_waitcnt vmcnt(4) lgkmcnt(0)" ::: "memory");
        __builtin_amdgcn_s_barrier();
    }

    // ---- tail: tile 14 (buf0) with last stage, then tile 15 (buf1)
    stageB(15 * 128, Bs1);
    compute(As0, Bs0);
    packA(r1a, r1b, r1c, r1d, As1);
    asm volatile("s_waitcnt vmcnt(0) lgkmcnt(0)" ::: "memory");
    __builtin_amdgcn_s_barrier();

    compute(As1, Bs1);
    __syncthreads();  // full drain before epilogue aliases the stage buffers

    // ---- scatter H tile (bf16). D layout: col=lane&15, row=q*4+reg [m89]
#pragma unroll
    for (int j = 0; j < 2; ++j) {
        int col = w * 32 + j * 16 + mr;
#pragma unroll
        for (int r = 0; r < 4; ++r) {
            Ht[(q * 4 + r) * 136 + col] = f2bf(acc[0][j][r]);
            Ht[(16 + q * 4 + r) * 136 + col] = f2bf(acc[1][j][r]);
        }
    }
    __syncthreads();

    // ---- P[32x128] = Ht @ W^T  (W fp32 from global, L1/L2-hot)
    floatx4 p[2][2];
#pragma unroll
    for (int i = 0; i < 2; ++i)
#pragma unroll
        for (int j = 0; j < 2; ++j) p[i][j] = (floatx4){0.f, 0.f, 0.f, 0.f};

#pragma unroll
    for (int ks = 0; ks < 4; ++ks) {
        short8 ha0 = *(const short8*)(Ht + mr * 136 + ks * 32 + q * 8);
        short8 ha1 = *(const short8*)(Ht + (mr + 16) * 136 + ks * 32 + q * 8);
#pragma unroll
        for (int j = 0; j < 2; ++j) {
            const float* wp = W + (w * 32 + j * 16 + mr) * F_DIM + ks * 32 + q * 8;
            short8 wb = pack8(((const float4*)wp)[0], ((const float4*)wp)[1]);
            p[0][j] = __builtin_amdgcn_mfma_f32_16x16x32_bf16(ha0, wb, p[0][j], 0, 0, 0);
            p[1][j] = __builtin_amdgcn_mfma_f32_16x16x32_bf16(ha1, wb, p[1][j], 0, 0, 0);
        }
    }

    // ---- bias add, scatter P (fp32) for row-major LN
#pragma unroll
    for (int j = 0; j < 2; ++j) {
        int col = w * 32 + j * 16 + mr;
        float bcol = bias[col];
#pragma unroll
        for (int r = 0; r < 4; ++r) {
            Pt[q * 4 + r][col] = p[0][j][r] + bcol;
            Pt[16 + q * 4 + r][col] = p[1][j][r] + bcol;
        }
    }
    __syncthreads();

    // ---- LayerNorm + ReLU: 8 lanes per row, 16 values each
    const int row = t >> 3;
    const int seg = t & 7;
    float v[16];
    float s = 0.f, s2 = 0.f;
#pragma unroll
    for (int u = 0; u < 16; ++u) {
        v[u] = Pt[row][seg * 16 + u];
        s += v[u];
        s2 += v[u] * v[u];
    }
    s += __shfl_xor(s, 1);  s2 += __shfl_xor(s2, 1);
    s += __shfl_xor(s, 2);  s2 += __shfl_xor(s2, 2);
    s += __shfl_xor(s, 4);  s2 += __shfl_xor(s2, 4);
    float mu = s * (1.0f / 128.0f);
    float var = s2 * (1.0f / 128.0f) - mu * mu;
    float rs = rsqrtf(var + LN_EPS);

    float4 o[4];
    float* of = (float*)o;
#pragma unroll
    for (int u = 0; u < 16; ++u) {
        int d = seg * 16 + u;
        float y = (v[u] - mu) * rs * gamma[d] + beta[d];
        of[u] = fmaxf(y, 0.0f);
    }
    float4* dst = (float4*)(out + ((size_t)bb * N_DIM + m0 + row) * F_DIM + seg * 16);
    dst[0] = o[0]; dst[1] = o[1]; dst[2] = o[2]; dst[3] = o[3];
}

// ---------------------------------------------------------------------------
extern "C" void kernel_launch(void* const* d_in, const int* in_sizes, int n_in,
                              void* d_out, int out_size, void* d_ws, size_t ws_size,
                              hipStream_t stream) {
    const float* A     = (const float*)d_in[0];
    const float* X     = (const float*)d_in[1];
    const float* W     = (const float*)d_in[2];
    const float* bias  = (const float*)d_in[3];
    const float* gamma = (const float*)d_in[4];
    const float* beta  = (const float*)d_in[5];
    float* out = (float*)d_out;

    ushort* Xt = (ushort*)d_ws;  // 4 MB bf16

    k_transpose<<<dim3(32, 2, 8), 256, 0, stream>>>(X, Xt);
    k_fused<<<dim3(512), 256, 0, stream>>>(A, Xt, W, bias, gamma, beta, out);
}